// Round 1
// baseline (1520.631 us; speedup 1.0000x reference)
//
#include <hip/hip_runtime.h>
#include <hip/hip_bf16.h>
#include <math.h>

// MaskedAttention: B=16, T=2048, C=1024, D=64, fp32.
// Round 1: correct fp32 baseline.
//   Phase 1: fused QKV projection (tiled vector-FMA GEMM, 48 FMA / 7 LDS reads per k)
//   Phase 2: flash-style causal attention, K/V rows streamed from L2 via
//            wave-broadcast loads (no LDS), online softmax w/ deferred rescale.

#define B_ 16
#define T_ 2048
#define C_ 1024
#define D_ 64
#define BT_ (B_ * T_)

// ---------------------------------------------------------------- projection
constexpr int BM = 64, BK = 32;

__global__ __launch_bounds__(256) void qkv_proj_kernel(
    const float* __restrict__ x, const float* __restrict__ Wq,
    const float* __restrict__ Wk, const float* __restrict__ Wv,
    float* __restrict__ q, float* __restrict__ k, float* __restrict__ v)
{
    __shared__ float xs[BM][BK + 4];   // +4 pad keeps float4 alignment, breaks bank stride
    __shared__ float ws[BK][192];      // Wq|Wk|Wv slabs side by side

    const int tid  = threadIdx.x;
    const int row0 = blockIdx.x * BM;
    const int rowg = tid >> 4;         // 0..15
    const int colg = tid & 15;         // 0..15
    const int r0   = rowg * 4;         // 4-row micro-tile
    const int c0   = colg * 12;        // 12-col micro-tile (0..191)

    float acc[4][12];
    #pragma unroll
    for (int i = 0; i < 4; ++i)
        #pragma unroll
        for (int j = 0; j < 12; ++j) acc[i][j] = 0.f;

    for (int kb = 0; kb < C_; kb += BK) {
        // stage x tile: 64 rows x 32 k, 2 float4 per thread, coalesced
        #pragma unroll
        for (int i = 0; i < 2; ++i) {
            int idx = i * 256 + tid;
            int rr = idx >> 3, kk = (idx & 7) << 2;
            *(float4*)&xs[rr][kk] =
                *(const float4*)&x[(size_t)(row0 + rr) * C_ + kb + kk];
        }
        // stage all three W k-slices: 32 x 64 each
        #pragma unroll
        for (int i = 0; i < 2; ++i) {
            int idx = i * 256 + tid;
            int kk = idx >> 4, cc = (idx & 15) << 2;
            size_t g = (size_t)(kb + kk) * D_ + cc;
            *(float4*)&ws[kk][cc]       = *(const float4*)&Wq[g];
            *(float4*)&ws[kk][64 + cc]  = *(const float4*)&Wk[g];
            *(float4*)&ws[kk][128 + cc] = *(const float4*)&Wv[g];
        }
        __syncthreads();

        #pragma unroll
        for (int kk = 0; kk < BK; ++kk) {
            float a[4], bf[12];
            #pragma unroll
            for (int i = 0; i < 4; ++i) a[i] = xs[r0 + i][kk];
            *(float4*)&bf[0] = *(float4*)&ws[kk][c0];
            *(float4*)&bf[4] = *(float4*)&ws[kk][c0 + 4];
            *(float4*)&bf[8] = *(float4*)&ws[kk][c0 + 8];
            #pragma unroll
            for (int i = 0; i < 4; ++i)
                #pragma unroll
                for (int j = 0; j < 12; ++j)
                    acc[i][j] = fmaf(a[i], bf[j], acc[i][j]);
        }
        __syncthreads();
    }

    // scatter 4x12 micro-tile into q/k/v
    #pragma unroll
    for (int i = 0; i < 4; ++i) {
        const size_t row = (size_t)(row0 + r0 + i);
        #pragma unroll
        for (int j = 0; j < 12; ++j) {
            int c = c0 + j;
            float* dst = (c < 64) ? q : (c < 128) ? k : v;
            dst[row * D_ + (c & 63)] = acc[i][j];
        }
    }
}

// ---------------------------------------------------------------- attention
// One wave per 16 q-rows. lane = (r 0..15, qtr 0..3): each lane holds
// Q[r][qtr*16 .. +16) and accumulates O[r][qtr*16 .. +16).
// K/V rows are read directly from global (L2-resident, wave-broadcast).
__global__ __launch_bounds__(64) void attn_kernel(
    const float* __restrict__ q, const float* __restrict__ k,
    const float* __restrict__ v, float* __restrict__ out)
{
    // grid = 2048 blocks, b-major; bijective XCD swizzle (2048 % 8 == 0)
    int bid = blockIdx.x;
    int swz = (bid & 7) * 256 + (bid >> 3);
    const int b  = swz >> 7;      // 0..15
    const int qt = swz & 127;     // 0..127 (16-row q tiles)

    const int lane = threadIdx.x;
    const int r    = lane & 15;
    const int qtr  = lane >> 4;   // 0..3, 16-wide d/k slice
    const int rowg = qt * 16 + r;

    const float* Qp = q + ((size_t)(b * T_ + rowg)) * D_ + qtr * 16;
    float4 qf[4];
    #pragma unroll
    for (int c = 0; c < 4; ++c) qf[c] = *(const float4*)&Qp[c * 4];

    const float* Kb = k + (size_t)b * T_ * D_ + qtr * 16;
    const float* Vb = v + (size_t)b * T_ * D_ + qtr * 16;

    float4 o[4];
    #pragma unroll
    for (int c = 0; c < 4; ++c) o[c] = make_float4(0.f, 0.f, 0.f, 0.f);
    float m = -INFINITY, l = 0.f;

    const int jmax = qt * 16 + 15;
    #pragma unroll 2
    for (int j = 0; j <= jmax; ++j) {
        // QK^T partial over this lane's 16-k slice, then 4-lane reduce
        const float4* kp = (const float4*)&Kb[(size_t)j * D_];
        float part = 0.f;
        #pragma unroll
        for (int c = 0; c < 4; ++c) {
            float4 kv = kp[c];
            part = fmaf(qf[c].x, kv.x, part);
            part = fmaf(qf[c].y, kv.y, part);
            part = fmaf(qf[c].z, kv.z, part);
            part = fmaf(qf[c].w, kv.w, part);
        }
        part += __shfl_xor(part, 16);
        part += __shfl_xor(part, 32);

        float s = (j <= rowg) ? part * 0.03125f : -INFINITY;  // 1/sqrt(1024)

        // online softmax, deferred rescale (rare branch, wave-uniform test)
        float mn = fmaxf(m, s);
        if (__any(mn > m)) {
            float corr = __expf(m - mn);   // first iter: exp(-inf)=0 zeroes l,o
            l *= corr;
            #pragma unroll
            for (int c = 0; c < 4; ++c) {
                o[c].x *= corr; o[c].y *= corr; o[c].z *= corr; o[c].w *= corr;
            }
            m = mn;
        }
        float p = __expf(s - m);           // masked j: exp(-inf)=0
        l += p;

        const float4* vp = (const float4*)&Vb[(size_t)j * D_];
        #pragma unroll
        for (int c = 0; c < 4; ++c) {
            float4 vv = vp[c];
            o[c].x = fmaf(p, vv.x, o[c].x);
            o[c].y = fmaf(p, vv.y, o[c].y);
            o[c].z = fmaf(p, vv.z, o[c].z);
            o[c].w = fmaf(p, vv.w, o[c].w);
        }
    }

    const float inv = 1.f / l;
    float* op = out + ((size_t)(b * T_ + rowg)) * D_ + qtr * 16;
    #pragma unroll
    for (int c = 0; c < 4; ++c) {
        float4 ov = o[c];
        ov.x *= inv; ov.y *= inv; ov.z *= inv; ov.w *= inv;
        *(float4*)&op[c * 4] = ov;
    }
}

// ---------------------------------------------------------------- launch
extern "C" void kernel_launch(void* const* d_in, const int* in_sizes, int n_in,
                              void* d_out, int out_size, void* d_ws, size_t ws_size,
                              hipStream_t stream) {
    const float* x  = (const float*)d_in[0];
    const float* Wq = (const float*)d_in[1];
    const float* Wk = (const float*)d_in[2];
    const float* Wv = (const float*)d_in[3];
    float* out = (float*)d_out;

    // workspace: q | k | v, each BT_ x D_ fp32 (25.2 MB total)
    float* q = (float*)d_ws;
    float* k = q + (size_t)BT_ * D_;
    float* v = k + (size_t)BT_ * D_;

    qkv_proj_kernel<<<BT_ / BM, 256, 0, stream>>>(x, Wq, Wk, Wv, q, k, v);
    attn_kernel<<<B_ * (T_ / 16), 64, 0, stream>>>(q, k, v, out);
}

// Round 4
// 315.920 us; speedup vs baseline: 4.8133x; 4.8133x over previous
//
#include <hip/hip_runtime.h>
#include <math.h>

// MaskedAttention B=16 T=2048 C=1024 D=64 — bf16 MFMA, compensated numerics.
// prep:  W[1024][64]x3 (f32) -> WT_h/WT_l bf16 [192][1024]  (transpose + hi/lo split)
// proj:  q(f32), k(bf16 row-major), v(bf16 TRANSPOSED vt[b][d][t]) via 3-term MFMA
// attn:  flash, 16x16x32 MFMA, split-Q QK^T, online softmax, PV via LDS P-buffer

#define B_ 16
#define T_ 2048
#define C_ 1024
#define D_ 64
#define BT_ (B_ * T_)

typedef __attribute__((ext_vector_type(8))) short short8;
typedef __attribute__((ext_vector_type(4))) float f32x4;

__device__ __forceinline__ unsigned short f2bf(float f) {
    unsigned u = __float_as_uint(f);
    return (unsigned short)((u + 0x7fffu + ((u >> 16) & 1u)) >> 16);
}
__device__ __forceinline__ float bf2f(unsigned short h) {
    return __uint_as_float(((unsigned)h) << 16);
}
#define MFMA16(a, b, c) __builtin_amdgcn_mfma_f32_16x16x32_bf16((a), (b), (c), 0, 0, 0)

// ------------------------------------------------------------------ W prep
// WT[n][c], n = 0..191 over (Wq|Wk|Wv) cols, hi/lo bf16 split. 48 blocks x 256.
__global__ __launch_bounds__(256) void wprep_kernel(
    const float* __restrict__ Wq, const float* __restrict__ Wk,
    const float* __restrict__ Wv, short* __restrict__ WTh, short* __restrict__ WTl)
{
    int id = blockIdx.x * 256 + threadIdx.x;     // 0..12287
    int n  = id >> 6;                            // 0..191
    int c0 = (id & 63) << 4;                     // 0..1008
    const float* W = (n < 64) ? Wq : (n < 128) ? Wk : Wv;
    int d = n & 63;
    short8 h0, h1, l0, l1;
    #pragma unroll
    for (int i = 0; i < 8; ++i) {
        float w = W[(size_t)(c0 + i) * 64 + d];
        unsigned short hh = f2bf(w);
        h0[i] = (short)hh; l0[i] = (short)f2bf(w - bf2f(hh));
        float w2 = W[(size_t)(c0 + 8 + i) * 64 + d];
        unsigned short hh2 = f2bf(w2);
        h1[i] = (short)hh2; l1[i] = (short)f2bf(w2 - bf2f(hh2));
    }
    size_t o = (size_t)n * 1024 + c0;
    *(short8*)&WTh[o] = h0; *(short8*)&WTh[o + 8] = h1;
    *(short8*)&WTl[o] = l0; *(short8*)&WTl[o + 8] = l1;
}

// ------------------------------------------------------------------ projection
// 512 blocks x 256 thr. Block = 64 rows. Wave w owns output cols 48w..48w+47.
__global__ __launch_bounds__(256) void qkv_mfma_kernel(
    const float* __restrict__ x, const short* __restrict__ WTh,
    const short* __restrict__ WTl, float* __restrict__ qf,
    short* __restrict__ kbf, short* __restrict__ vtb)
{
    __shared__ alignas(16) short xh[64 * 64];   // [row][64], 16B units XOR-swizzled
    __shared__ alignas(16) short xl[64 * 64];

    const int tid = threadIdx.x;
    const int row0 = blockIdx.x * 64;
    const int lane = tid & 63, w = tid >> 6;
    const int lr = lane & 15, lg = lane >> 4;
    const int sr = tid >> 2, sc = (tid & 3) * 16;   // staging role: row sr, cols sc..sc+15

    f32x4 acc[4][3];
    #pragma unroll
    for (int mt = 0; mt < 4; ++mt)
        #pragma unroll
        for (int gi = 0; gi < 3; ++gi) acc[mt][gi] = (f32x4){0.f, 0.f, 0.f, 0.f};

    for (int kb = 0; kb < C_; kb += 64) {
        // load + split 16 f32 of x per thread
        float xv[16];
        const float* xp = &x[(size_t)(row0 + sr) * C_ + kb + sc];
        *(float4*)&xv[0]  = *(const float4*)&xp[0];
        *(float4*)&xv[4]  = *(const float4*)&xp[4];
        *(float4*)&xv[8]  = *(const float4*)&xp[8];
        *(float4*)&xv[12] = *(const float4*)&xp[12];
        short8 h0, h1, l0, l1;
        #pragma unroll
        for (int i = 0; i < 8; ++i) {
            unsigned short hh = f2bf(xv[i]);
            h0[i] = (short)hh; l0[i] = (short)f2bf(xv[i] - bf2f(hh));
            unsigned short hh2 = f2bf(xv[8 + i]);
            h1[i] = (short)hh2; l1[i] = (short)f2bf(xv[8 + i] - bf2f(hh2));
        }
        __syncthreads();   // prior iteration's reads complete
        {
            int u0 = (sc >> 3), u1 = u0 + 1;
            *(short8*)&xh[sr * 64 + (u0 ^ (sr & 7)) * 8] = h0;
            *(short8*)&xh[sr * 64 + (u1 ^ (sr & 7)) * 8] = h1;
            *(short8*)&xl[sr * 64 + (u0 ^ (sr & 7)) * 8] = l0;
            *(short8*)&xl[sr * 64 + (u1 ^ (sr & 7)) * 8] = l1;
        }
        __syncthreads();

        #pragma unroll
        for (int kc = 0; kc < 2; ++kc) {
            short8 ah[4], al[4];
            #pragma unroll
            for (int mt = 0; mt < 4; ++mt) {
                int r = mt * 16 + lr;
                int usw = (kc * 4 + lg) ^ (r & 7);
                ah[mt] = *(short8*)&xh[r * 64 + usw * 8];
                al[mt] = *(short8*)&xl[r * 64 + usw * 8];
            }
            #pragma unroll
            for (int gi = 0; gi < 3; ++gi) {
                int n = (3 * w + gi) * 16 + lr;
                size_t wo = (size_t)n * 1024 + kb + kc * 32 + lg * 8;
                short8 wh = *(const short8*)&WTh[wo];
                short8 wl = *(const short8*)&WTl[wo];
                #pragma unroll
                for (int mt = 0; mt < 4; ++mt) {
                    acc[mt][gi] = MFMA16(ah[mt], wh, acc[mt][gi]);
                    acc[mt][gi] = MFMA16(ah[mt], wl, acc[mt][gi]);
                    acc[mt][gi] = MFMA16(al[mt], wh, acc[mt][gi]);
                }
            }
        }
    }

    // epilogue: cols 0-63 -> q (f32), 64-127 -> k (bf16), 128-191 -> v^T (bf16)
    #pragma unroll
    for (int mt = 0; mt < 4; ++mt) {
        int rbase = row0 + mt * 16 + lg * 4;
        #pragma unroll
        for (int gi = 0; gi < 3; ++gi) {
            int g = 3 * w + gi;
            f32x4 a = acc[mt][gi];
            int col = g * 16 + lr;
            if (g < 4) {
                #pragma unroll
                for (int reg = 0; reg < 4; ++reg)
                    qf[(size_t)(rbase + reg) * 64 + col] = a[reg];
            } else if (g < 8) {
                #pragma unroll
                for (int reg = 0; reg < 4; ++reg)
                    kbf[(size_t)(rbase + reg) * 64 + (col - 64)] = (short)f2bf(a[reg]);
            } else {
                int d = col - 128;
                int bb = rbase >> 11, t0 = rbase & (T_ - 1);
                short4 pk;
                pk.x = (short)f2bf(a[0]); pk.y = (short)f2bf(a[1]);
                pk.z = (short)f2bf(a[2]); pk.w = (short)f2bf(a[3]);
                *(short4*)&vtb[((size_t)(bb * 64 + d) << 11) + t0] = pk;
            }
        }
    }
}

// ------------------------------------------------------------------ attention
// 512 blocks x 256 thr. Block = (b, 64 q-rows). Wave = 16 q-rows. j-tiles of 64.
__global__ __launch_bounds__(256) void attn_mfma_kernel(
    const float* __restrict__ qf, const short* __restrict__ kbf,
    const short* __restrict__ vtb, float* __restrict__ out)
{
    __shared__ alignas(16) short kbuf[64 * 64];       // K-tile  [kj][d], swizzled units
    __shared__ alignas(16) short vbuf[64 * 64];       // V^T-tile [d][kj], swizzled units
    __shared__ alignas(16) short pbuf[4 * 16 * 64];   // per-wave P [16][64], swizzled

    const int bid = blockIdx.x;
    const int b  = bid & 15;                 // bid%8 pins batch to an XCD pair
    const int qt = 31 - (bid >> 4);          // heavy causal tiles dispatched first
    const int tid = threadIdx.x;
    const int lane = tid & 63, w = tid >> 6;
    const int lr = lane & 15, lg = lane >> 4;
    const int qrow0 = qt * 64 + w * 16;      // within-batch q-row base for this wave
    const size_t base_tok = (size_t)b * T_;

    // Q fragments, scaled by 1/sqrt(C)=1/32 (exact pow2), split hi/lo
    short8 qh[2], ql[2];
    #pragma unroll
    for (int kc = 0; kc < 2; ++kc) {
        const float* qp = &qf[(base_tok + qrow0 + lr) * 64 + kc * 32 + lg * 8];
        float4 q0 = *(const float4*)qp;
        float4 q1 = *(const float4*)(qp + 4);
        float qs[8] = {q0.x, q0.y, q0.z, q0.w, q1.x, q1.y, q1.z, q1.w};
        #pragma unroll
        for (int i = 0; i < 8; ++i) {
            float v = qs[i] * 0.03125f;
            unsigned short hh = f2bf(v);
            qh[kc][i] = (short)hh;
            ql[kc][i] = (short)f2bf(v - bf2f(hh));
        }
    }

    f32x4 o[4];
    #pragma unroll
    for (int dt = 0; dt < 4; ++dt) o[dt] = (f32x4){0.f, 0.f, 0.f, 0.f};
    float m[4]    = {-INFINITY, -INFINITY, -INFINITY, -INFINITY};
    float lsum[4] = {0.f, 0.f, 0.f, 0.f};

    // staging roles: thread -> row sr (0..63), two 16B units su*2, su*2+1
    const int sr = tid >> 2, su = tid & 3;
    const short* Kb = kbf + base_tok * 64;          // [t][64]
    const short* Vb = vtb + (size_t)b * 64 * T_;    // [d][T]

    int4 kreg[2], vreg[2];
    auto load_regs = [&](int jt) {
        int j0 = jt * 64;
        #pragma unroll
        for (int c = 0; c < 2; ++c) {
            kreg[c] = *(const int4*)&Kb[(size_t)(j0 + sr) * 64 + (su * 2 + c) * 8];
            vreg[c] = *(const int4*)&Vb[(size_t)sr * T_ + j0 + (su * 2 + c) * 8];
        }
    };
    auto write_bufs = [&]() {
        #pragma unroll
        for (int c = 0; c < 2; ++c) {
            int usw = (su * 2 + c) ^ (sr & 7);
            *(int4*)&kbuf[sr * 64 + usw * 8] = kreg[c];
            *(int4*)&vbuf[sr * 64 + usw * 8] = vreg[c];
        }
    };

    load_regs(0);
    write_bufs();
    __syncthreads();

    for (int jt = 0; jt <= qt; ++jt) {
        if (jt < qt) load_regs(jt + 1);   // issue next tile's global loads early

        // ---- QK^T: S[16q][64j], split-Q compensated
        f32x4 s[4];
        #pragma unroll
        for (int nt = 0; nt < 4; ++nt) s[nt] = (f32x4){0.f, 0.f, 0.f, 0.f};
        #pragma unroll
        for (int kc = 0; kc < 2; ++kc)
            #pragma unroll
            for (int nt = 0; nt < 4; ++nt) {
                int kj = nt * 16 + lr;
                int usw = (kc * 4 + lg) ^ (kj & 7);
                short8 kf = *(short8*)&kbuf[kj * 64 + usw * 8];
                s[nt] = MFMA16(qh[kc], kf, s[nt]);
                s[nt] = MFMA16(ql[kc], kf, s[nt]);
            }

        // ---- causal mask (diagonal tile only)
        if (jt == qt) {
            int j0 = jt * 64;
            #pragma unroll
            for (int nt = 0; nt < 4; ++nt) {
                int j = j0 + nt * 16 + lr;
                #pragma unroll
                for (int reg = 0; reg < 4; ++reg)
                    if (j > qrow0 + lg * 4 + reg) s[nt][reg] = -INFINITY;
            }
        }

        // ---- online softmax (rows = lg*4+reg, reduce over the 16 lr lanes)
        float corr[4], psum[4] = {0.f, 0.f, 0.f, 0.f};
        #pragma unroll
        for (int reg = 0; reg < 4; ++reg) {
            float vmax = fmaxf(fmaxf(s[0][reg], s[1][reg]),
                               fmaxf(s[2][reg], s[3][reg]));
            vmax = fmaxf(vmax, __shfl_xor(vmax, 1));
            vmax = fmaxf(vmax, __shfl_xor(vmax, 2));
            vmax = fmaxf(vmax, __shfl_xor(vmax, 4));
            vmax = fmaxf(vmax, __shfl_xor(vmax, 8));
            float mnew = fmaxf(m[reg], vmax);
            corr[reg] = __expf(m[reg] - mnew);
            m[reg] = mnew;
        }
        #pragma unroll
        for (int nt = 0; nt < 4; ++nt)
            #pragma unroll
            for (int reg = 0; reg < 4; ++reg) {
                float p = __expf(s[nt][reg] - m[reg]);
                psum[reg] += p;
                int qr = lg * 4 + reg;            // P row
                int colj = nt * 16 + lr;          // P col
                int usw = (colj >> 3) ^ (qr & 7);
                pbuf[(w * 16 + qr) * 64 + usw * 8 + (colj & 7)] = (short)f2bf(p);
            }
        #pragma unroll
        for (int reg = 0; reg < 4; ++reg)
            lsum[reg] = lsum[reg] * corr[reg] + psum[reg];
        #pragma unroll
        for (int dt = 0; dt < 4; ++dt) {
            o[dt][0] *= corr[0]; o[dt][1] *= corr[1];
            o[dt][2] *= corr[2]; o[dt][3] *= corr[3];
        }

        // ---- PV: O += P[16x64] * V[64x64]  (P via wave-private LDS transpose)
        asm volatile("s_waitcnt lgkmcnt(0)" ::: "memory");
        __builtin_amdgcn_sched_barrier(0);
        short8 pf[2];
        #pragma unroll
        for (int kc = 0; kc < 2; ++kc) {
            int usw = (kc * 4 + lg) ^ (lr & 7);
            pf[kc] = *(short8*)&pbuf[(w * 16 + lr) * 64 + usw * 8];
        }
        #pragma unroll
        for (int dt = 0; dt < 4; ++dt)
            #pragma unroll
            for (int kc = 0; kc < 2; ++kc) {
                int d = dt * 16 + lr;
                int usw = (kc * 4 + lg) ^ (d & 7);
                short8 vf = *(short8*)&vbuf[d * 64 + usw * 8];
                o[dt] = MFMA16(pf[kc], vf, o[dt]);
            }

        if (jt < qt) {
            __syncthreads();      // everyone done reading current K/V tile
            write_bufs();
            __syncthreads();
        }
    }

    // ---- epilogue: row-sum reduce, normalize, store f32
    #pragma unroll
    for (int reg = 0; reg < 4; ++reg) {
        lsum[reg] += __shfl_xor(lsum[reg], 1);
        lsum[reg] += __shfl_xor(lsum[reg], 2);
        lsum[reg] += __shfl_xor(lsum[reg], 4);
        lsum[reg] += __shfl_xor(lsum[reg], 8);
        lsum[reg] = 1.f / lsum[reg];
    }
    #pragma unroll
    for (int dt = 0; dt < 4; ++dt)
        #pragma unroll
        for (int reg = 0; reg < 4; ++reg)
            out[(base_tok + qrow0 + lg * 4 + reg) * 64 + dt * 16 + lr] =
                o[dt][reg] * lsum[reg];
}

// ------------------------------------------------------------------ launch
extern "C" void kernel_launch(void* const* d_in, const int* in_sizes, int n_in,
                              void* d_out, int out_size, void* d_ws, size_t ws_size,
                              hipStream_t stream) {
    const float* x  = (const float*)d_in[0];
    const float* Wq = (const float*)d_in[1];
    const float* Wk = (const float*)d_in[2];
    const float* Wv = (const float*)d_in[3];
    float* out = (float*)d_out;

    // workspace: qf f32 8MB | kbf bf16 4MB | vtb bf16 4MB | WTh 384KB | WTl 384KB
    float* qf  = (float*)d_ws;
    short* kbf = (short*)(qf + (size_t)BT_ * 64);
    short* vtb = kbf + (size_t)BT_ * 64;
    short* WTh = vtb + (size_t)BT_ * 64;
    short* WTl = WTh + (size_t)192 * 1024;

    wprep_kernel<<<48, 256, 0, stream>>>(Wq, Wk, Wv, WTh, WTl);
    qkv_mfma_kernel<<<512, 256, 0, stream>>>(x, WTh, WTl, qf, kbf, vtb);
    attn_mfma_kernel<<<512, 256, 0, stream>>>(qf, kbf, vtb, out);
}